// Round 8
// baseline (611.575 us; speedup 1.0000x reference)
//
#include <hip/hip_runtime.h>
#include <math.h>

// NoiScaleModule: B=128, C=32(seq), S=512(d_model), EMB=256, NHEAD=8, DFF=2048
// All tensors FLOAT32. Outputs concat flat: res[2M], down_x[2M], fa[2M], up[2M]
//
// R8: dispatch-chain reduction. up1@up2 collapsed into one GEMM via precomputed
// Wc=up2·up1 (hi/lo) + exact bc. Two heterogeneous mega-dispatches:
//   mega1 = freq-Wa mfma3 + t-qkv plain mfma   (both consume x; 2048 blocks)
//   mega2 = r-qkv mfma3 + up mfma3             (same A = fa hi/lo; 2048 blocks)
// t-attn moved early (before r-qkv clobbers BIGu), result parked in U3.
// Prep consolidated: combined Wa/Wm split; lbpack+up2lo+rinlo folded into wcvt.

#define NROW 4096
#define NOUT 2097152

typedef __attribute__((ext_vector_type(8))) short short8;
typedef __attribute__((ext_vector_type(4))) float floatx4;

__device__ __forceinline__ unsigned short f2bf(float f) {
    union { float f; unsigned u; } v; v.f = f;
    return (unsigned short)((v.u + 0x7fffu + ((v.u >> 16) & 1u)) >> 16);
}
__device__ __forceinline__ float bf2f(unsigned short h) {
    union { unsigned u; float f; } v; v.u = ((unsigned)h) << 16;
    return v.f;
}
__device__ __forceinline__ float ldv(const float* p, size_t i) { return p[i]; }
__device__ __forceinline__ float ldv(const unsigned short* p, size_t i) { return bf2f(p[i]); }

__device__ __forceinline__ void gload16(const unsigned short* g, unsigned short* l) {
    __builtin_amdgcn_global_load_lds((const __attribute__((address_space(1))) void*)g,
                                     (__attribute__((address_space(3))) void*)l, 16, 0, 0);
}

// ---------------- prep: cos/sin tables tab[n][k], n<512, k<256 ----------------
__global__ __launch_bounds__(256) void tab_kernel(float* __restrict__ tabC, float* __restrict__ tabS)
{
    int n = blockIdx.x, k = threadIdx.x;
    int m = (n * k) & 511;
    float th = (float)m * 0.01227184630308513f;  // 2*pi/512
    float s, c; sincosf(th, &s, &c);
    tabC[n * 256 + k] = c;
    tabS[n * 256 + k] = s;
}

__global__ __launch_bounds__(256) void wa_kernel(const float* __restrict__ l1_re, const float* __restrict__ l1_im,
                                                 const float* __restrict__ tabC, const float* __restrict__ tabS,
                                                 float* __restrict__ Wa)
{
    int n  = blockIdx.x;
    int ep = blockIdx.y * 256 + threadIdx.x;
    const float inv = 0.04419417382415922f;  // 1/sqrt(512)
    float acc = 0.f;
    if (ep < 256) {
        for (int k = 0; k < 128; ++k) {
            float c = tabC[n * 256 + k], s = tabS[n * 256 + k];
            acc += c * l1_re[k * 256 + ep] + s * l1_im[k * 256 + ep];
        }
    } else {
        int e = ep - 256;
        for (int k = 0; k < 128; ++k) {
            float c = tabC[n * 256 + k], s = tabS[n * 256 + k];
            acc += c * l1_im[k * 256 + e] - s * l1_re[k * 256 + e];
        }
    }
    Wa[(size_t)ep * 512 + n] = acc * inv;
}

__global__ __launch_bounds__(256) void wm_kernel(const float* __restrict__ lc_w,
                                                 const float* __restrict__ tabC, const float* __restrict__ tabS,
                                                 float* __restrict__ Wm)
{
    __shared__ float lw[512];
    int s  = blockIdx.x;
    int kk = blockIdx.y * 256 + threadIdx.x;
    for (int i = threadIdx.x; i < 512; i += 256) lw[i] = lc_w[s * 512 + i];
    __syncthreads();
    const float inv = 0.04419417382415922f;
    float acc = 0.f;
    if (kk < 256) {
        int k = kk;
        for (int n = 0; n < 512; ++n) acc += tabC[n * 256 + k] * lw[n];
        acc *= (k == 0) ? inv : 2.f * inv;
    } else {
        int k = kk - 256;
        if (k == 0) acc = 0.f;
        else {
            for (int n = 0; n < 512; ++n) acc += tabS[n * 256 + k] * lw[n];
            acc *= -2.f * inv;
        }
    }
    Wm[(size_t)s * 512 + kk] = acc;
}

// combined Wa/Wm hi-lo split: src = [Wa(262144) | Wm(262144)] contiguous
__global__ __launch_bounds__(256) void cvt2_kernel(const float* __restrict__ src,
                                                   unsigned short* __restrict__ h1, unsigned short* __restrict__ l1,
                                                   unsigned short* __restrict__ h2, unsigned short* __restrict__ l2)
{
    int i = blockIdx.x * 256 + threadIdx.x;   // 0..524287
    float v = src[i];
    unsigned short h = f2bf(v);
    unsigned short l = f2bf(v - bf2f(h));
    if (i < 262144) { h1[i] = h; l1[i] = l; }
    else            { h2[i - 262144] = h; l2[i - 262144] = l; }
}

// 10 hi weights + LB pack (lb|zeros) + up2 lo + r_in lo, one dispatch
__global__ __launch_bounds__(256) void wcvt_kernel(
    const float* s0, const float* s1, const float* s2, const float* s3, const float* s4,
    const float* s5, const float* s6, const float* s7, const float* s8, const float* s9,
    unsigned short* __restrict__ o,
    const float* __restrict__ lbre, const float* __restrict__ lbim, float* __restrict__ LB,
    const float* __restrict__ up2w, unsigned short* __restrict__ up2lo,
    const float* __restrict__ rinw, unsigned short* __restrict__ rinlo)
{
    int i = blockIdx.x * 256 + threadIdx.x;
    if (i >= 7865344) return;
    if (i < 6815744) {
        const float* s; int off;
        if (i < 3145728) {
            if (i < 1048576) { if (i < 786432) { s = s0; off = 0; } else { s = s1; off = 786432; } }
            else             { if (i < 2097152) { s = s2; off = 1048576; } else { s = s3; off = 2097152; } }
        } else {
            if (i < 5242880) {
                if (i < 3932160) { s = s4; off = 3145728; }
                else if (i < 4194304) { s = s5; off = 3932160; }
                else { s = s6; off = 4194304; }
            } else {
                if (i < 6291456) { s = s7; off = 5242880; }
                else if (i < 6553600) { s = s8; off = 6291456; }
                else { s = s9; off = 6553600; }
            }
        }
        o[i] = f2bf(s[i - off]);
    } else if (i < 6816768) {
        int j = i - 6815744;   // 0..1023
        LB[j] = (j < 256) ? lbre[j] : (j < 512 ? lbim[j - 256] : 0.f);
    } else if (i < 7078912) {
        int j = i - 6816768;   // up2 lo
        float v = up2w[j];
        up2lo[j] = f2bf(v - bf2f(f2bf(v)));
    } else {
        int j = i - 7078912;   // r_in lo
        float v = rinw[j];
        rinlo[j] = f2bf(v - bf2f(f2bf(v)));
    }
}

// up1_w transpose + hi/lo split: out[s*512+a] = split(up1_w[a*512+s])
__global__ __launch_bounds__(256) void up1t_kernel(const float* __restrict__ up1w,
                                                   unsigned short* __restrict__ th, unsigned short* __restrict__ tl)
{
    int i = blockIdx.x * 256 + threadIdx.x;   // 0..262143
    int s = i >> 9, a = i & 511;
    float v = up1w[a * 512 + s];
    unsigned short h = f2bf(v);
    th[i] = h;
    tl[i] = f2bf(v - bf2f(h));
}

// bc[n] = sum_k up2_w[n,k]*up1_b[k] + up2_b[n]  (exact f32)
__global__ __launch_bounds__(256) void bc_kernel(const float* __restrict__ up1b, const float* __restrict__ up2w,
                                                 const float* __restrict__ up2b, float* __restrict__ bc)
{
    int n = blockIdx.x * 256 + threadIdx.x;
    if (n >= 512) return;
    float a = 0.f;
    for (int k = 0; k < 512; ++k) a += up2w[n * 512 + k] * up1b[k];
    bc[n] = a + up2b[n];
}

// x -> hi/lo bf16 + f32 copy (down_x output)
__global__ __launch_bounds__(256) void xsplit_kernel(const float* __restrict__ a, unsigned short* __restrict__ hi,
                                                     unsigned short* __restrict__ lo, float* __restrict__ cp, int n)
{
    for (int i = blockIdx.x * 256 + threadIdx.x; i < n; i += gridDim.x * 256) {
        float v = a[i];
        unsigned short h = f2bf(v);
        hi[i] = h;
        lo[i] = f2bf(v - bf2f(h));
        cp[i] = v;
    }
}

// ---------------- MFMA GEMM: C[M,N] = A[M,K](bf16) @ W[N,K](bf16)^T + bias ----------------
template <int TM, int TN, int ACT, int WF, int WBF, int SPLIT2>
__global__ __launch_bounds__(256) void gemm_mfma(
    const unsigned short* __restrict__ A, const unsigned short* __restrict__ W,
    const float* __restrict__ bias, float* __restrict__ Cf, float* __restrict__ Cf2,
    unsigned short* __restrict__ Cb, int N, int K)
{
    constexpr int MI = TM / 32, NJ = TN / 32;
    constexpr int ARW = TM / 4, BRW = TN / 4;
    __shared__ unsigned short As[TM * 32];
    __shared__ unsigned short Bs[TN * 32];
    const int tid = threadIdx.x;
    const int wave = tid >> 6, lane = tid & 63;
    const int m0 = blockIdx.y * TM, n0 = blockIdx.x * TN;
    const int z = SPLIT2 ? blockIdx.z : 0;
    const int kLen = SPLIT2 ? (K >> 1) : K;
    const size_t kOff = (size_t)z * kLen;
    const int sr = lane >> 2, sc = (lane & 3) * 8;
    const unsigned short* aS = A + (size_t)(m0 + wave * ARW + sr) * K + kOff + sc;
    const unsigned short* wS = W + (size_t)(n0 + wave * BRW + sr) * K + kOff + sc;
    const int wm = (wave >> 1) * (TM / 2), wn = (wave & 1) * (TN / 2);
    const int fr = lane & 15, fko = (lane >> 4) * 8;

    floatx4 acc[MI][NJ];
#pragma unroll
    for (int i = 0; i < MI; ++i)
#pragma unroll
        for (int j = 0; j < NJ; ++j) acc[i][j] = (floatx4){0.f, 0.f, 0.f, 0.f};

    for (int k0 = 0; k0 < kLen; k0 += 32) {
#pragma unroll
        for (int c = 0; c < ARW / 16; ++c)
            gload16(aS + (size_t)(16 * c) * K + k0, &As[(wave * ARW + 16 * c) * 32]);
#pragma unroll
        for (int c = 0; c < BRW / 16; ++c)
            gload16(wS + (size_t)(16 * c) * K + k0, &Bs[(wave * BRW + 16 * c) * 32]);
        __syncthreads();
        short8 af[MI], bfr[NJ];
#pragma unroll
        for (int i = 0; i < MI; ++i) af[i] = *(const short8*)&As[(wm + i * 16 + fr) * 32 + fko];
#pragma unroll
        for (int j = 0; j < NJ; ++j) bfr[j] = *(const short8*)&Bs[(wn + j * 16 + fr) * 32 + fko];
#pragma unroll
        for (int i = 0; i < MI; ++i)
#pragma unroll
            for (int j = 0; j < NJ; ++j)
                acc[i][j] = __builtin_amdgcn_mfma_f32_16x16x32_bf16(af[i], bfr[j], acc[i][j], 0, 0, 0);
        __syncthreads();
    }
    const int r0 = m0 + wm + (lane >> 4) * 4;
#pragma unroll
    for (int i = 0; i < MI; ++i) {
#pragma unroll
        for (int j = 0; j < NJ; ++j) {
            int n = n0 + wn + j * 16 + fr;
            float bv = (z == 0) ? bias[n] : 0.f;
#pragma unroll
            for (int r = 0; r < 4; ++r) {
                int m = r0 + i * 16 + r;
                size_t idx = (size_t)m * N + n;
                float v = acc[i][j][r] + bv;
                if (ACT) v = fmaxf(v, 0.f);
                if (SPLIT2) {
                    if (z == 0) Cf[idx] = v; else Cf2[idx] = v;
                } else {
                    if (WF) Cf[idx] = v;
                    if (WBF) Cb[idx] = f2bf(v);
                }
            }
        }
    }
}

// ---------------- fused hi/lo 3-product MFMA GEMM (drops lo*lo) ----------
template <int TM, int TN, int ACT, int WCOPY, int WHILO>
__global__ __launch_bounds__(256) void gemm_mfma3(
    const unsigned short* __restrict__ Ah, const unsigned short* __restrict__ Al,
    const unsigned short* __restrict__ Wh, const unsigned short* __restrict__ Wl,
    const float* __restrict__ bias, float* __restrict__ Cf, float* __restrict__ Ccopy,
    unsigned short* __restrict__ Hh, unsigned short* __restrict__ Hl, int N, int K)
{
    constexpr int MI = TM / 32, NJ = TN / 32;
    constexpr int ARW = TM / 4, BRW = TN / 4;
    __shared__ unsigned short Ash[TM * 32];
    __shared__ unsigned short Asl[TM * 32];
    __shared__ unsigned short Bsh[TN * 32];
    __shared__ unsigned short Bsl[TN * 32];
    const int tid = threadIdx.x;
    const int wave = tid >> 6, lane = tid & 63;
    const int m0 = blockIdx.y * TM, n0 = blockIdx.x * TN;
    const int sr = lane >> 2, sc = (lane & 3) * 8;
    const size_t aoff = (size_t)(m0 + wave * ARW + sr) * K + sc;
    const size_t woff = (size_t)(n0 + wave * BRW + sr) * K + sc;
    const int wm = (wave >> 1) * (TM / 2), wn = (wave & 1) * (TN / 2);
    const int fr = lane & 15, fko = (lane >> 4) * 8;

    floatx4 acc[MI][NJ];
#pragma unroll
    for (int i = 0; i < MI; ++i)
#pragma unroll
        for (int j = 0; j < NJ; ++j) acc[i][j] = (floatx4){0.f, 0.f, 0.f, 0.f};

    for (int k0 = 0; k0 < K; k0 += 32) {
#pragma unroll
        for (int c = 0; c < ARW / 16; ++c) {
            gload16(Ah + aoff + (size_t)(16 * c) * K + k0, &Ash[(wave * ARW + 16 * c) * 32]);
            gload16(Al + aoff + (size_t)(16 * c) * K + k0, &Asl[(wave * ARW + 16 * c) * 32]);
        }
#pragma unroll
        for (int c = 0; c < BRW / 16; ++c) {
            gload16(Wh + woff + (size_t)(16 * c) * K + k0, &Bsh[(wave * BRW + 16 * c) * 32]);
            gload16(Wl + woff + (size_t)(16 * c) * K + k0, &Bsl[(wave * BRW + 16 * c) * 32]);
        }
        __syncthreads();
        short8 ah[MI], al[MI], bh[NJ], bl[NJ];
#pragma unroll
        for (int i = 0; i < MI; ++i) {
            ah[i] = *(const short8*)&Ash[(wm + i * 16 + fr) * 32 + fko];
            al[i] = *(const short8*)&Asl[(wm + i * 16 + fr) * 32 + fko];
        }
#pragma unroll
        for (int j = 0; j < NJ; ++j) {
            bh[j] = *(const short8*)&Bsh[(wn + j * 16 + fr) * 32 + fko];
            bl[j] = *(const short8*)&Bsl[(wn + j * 16 + fr) * 32 + fko];
        }
#pragma unroll
        for (int i = 0; i < MI; ++i)
#pragma unroll
            for (int j = 0; j < NJ; ++j) {
                acc[i][j] = __builtin_amdgcn_mfma_f32_16x16x32_bf16(al[i], bh[j], acc[i][j], 0, 0, 0);
                acc[i][j] = __builtin_amdgcn_mfma_f32_16x16x32_bf16(ah[i], bl[j], acc[i][j], 0, 0, 0);
                acc[i][j] = __builtin_amdgcn_mfma_f32_16x16x32_bf16(ah[i], bh[j], acc[i][j], 0, 0, 0);
            }
        __syncthreads();
    }
    const int r0 = m0 + wm + (lane >> 4) * 4;
#pragma unroll
    for (int i = 0; i < MI; ++i) {
#pragma unroll
        for (int j = 0; j < NJ; ++j) {
            int n = n0 + wn + j * 16 + fr;
            float bv = bias[n];
#pragma unroll
            for (int r = 0; r < 4; ++r) {
                int m = r0 + i * 16 + r;
                size_t idx = (size_t)m * N + n;
                float v = acc[i][j][r] + bv;
                if (ACT) v = fmaxf(v, 0.f);
                Cf[idx] = v;
                if (WCOPY) Ccopy[idx] = v;
                if (WHILO) {
                    unsigned short h = f2bf(v);
                    Hh[idx] = h;
                    Hl[idx] = f2bf(v - bf2f(h));
                }
            }
        }
    }
}

// ---------------- mega1: freq-Wa mfma3 (bx<8) + t-qkv plain (bx>=8), K=512, TM=TN=64 -----
__global__ __launch_bounds__(256) void mega1_kernel(
    const unsigned short* __restrict__ Xh, const unsigned short* __restrict__ Xl,
    const unsigned short* __restrict__ WaH, const unsigned short* __restrict__ WaL,
    const float* __restrict__ lb, float* __restrict__ Clow,
    const unsigned short* __restrict__ Wt, const float* __restrict__ tb,
    unsigned short* __restrict__ Cqkv)
{
    __shared__ unsigned short Ash[64 * 32];
    __shared__ unsigned short Asl[64 * 32];
    __shared__ unsigned short Bsh[64 * 32];
    __shared__ unsigned short Bsl[64 * 32];
    const int tid = threadIdx.x, wave = tid >> 6, lane = tid & 63;
    const int bx = blockIdx.x, m0 = blockIdx.y * 64;
    const bool freq = bx < 8;
    const int n0 = freq ? bx * 64 : (bx - 8) * 64;
    const int sr = lane >> 2, sc = (lane & 3) * 8;
    const size_t aoff = (size_t)(m0 + wave * 16 + sr) * 512 + sc;
    const size_t woff = (size_t)(n0 + wave * 16 + sr) * 512 + sc;
    const int wm = (wave >> 1) * 32, wn = (wave & 1) * 32;
    const int fr = lane & 15, fko = (lane >> 4) * 8;
    const int ldsb = (wave * 16) * 32;

    floatx4 acc[2][2];
#pragma unroll
    for (int i = 0; i < 2; ++i)
#pragma unroll
        for (int j = 0; j < 2; ++j) acc[i][j] = (floatx4){0.f, 0.f, 0.f, 0.f};

    if (freq) {
        for (int k0 = 0; k0 < 512; k0 += 32) {
            gload16(Xh + aoff + k0, &Ash[ldsb]);
            gload16(Xl + aoff + k0, &Asl[ldsb]);
            gload16(WaH + woff + k0, &Bsh[ldsb]);
            gload16(WaL + woff + k0, &Bsl[ldsb]);
            __syncthreads();
            short8 ah[2], al[2], bh[2], bl[2];
#pragma unroll
            for (int i = 0; i < 2; ++i) {
                ah[i] = *(const short8*)&Ash[(wm + i * 16 + fr) * 32 + fko];
                al[i] = *(const short8*)&Asl[(wm + i * 16 + fr) * 32 + fko];
            }
#pragma unroll
            for (int j = 0; j < 2; ++j) {
                bh[j] = *(const short8*)&Bsh[(wn + j * 16 + fr) * 32 + fko];
                bl[j] = *(const short8*)&Bsl[(wn + j * 16 + fr) * 32 + fko];
            }
#pragma unroll
            for (int i = 0; i < 2; ++i)
#pragma unroll
                for (int j = 0; j < 2; ++j) {
                    acc[i][j] = __builtin_amdgcn_mfma_f32_16x16x32_bf16(al[i], bh[j], acc[i][j], 0, 0, 0);
                    acc[i][j] = __builtin_amdgcn_mfma_f32_16x16x32_bf16(ah[i], bl[j], acc[i][j], 0, 0, 0);
                    acc[i][j] = __builtin_amdgcn_mfma_f32_16x16x32_bf16(ah[i], bh[j], acc[i][j], 0, 0, 0);
                }
            __syncthreads();
        }
        const int r0 = m0 + wm + (lane >> 4) * 4;
#pragma unroll
        for (int i = 0; i < 2; ++i)
#pragma unroll
            for (int j = 0; j < 2; ++j) {
                int n = n0 + wn + j * 16 + fr;
                float bv = lb[n];
#pragma unroll
                for (int r = 0; r < 4; ++r) {
                    int m = r0 + i * 16 + r;
                    Clow[(size_t)m * 512 + n] = fmaxf(acc[i][j][r] + bv, 0.f);
                }
            }
    } else {
        for (int k0 = 0; k0 < 512; k0 += 32) {
            gload16(Xh + aoff + k0, &Ash[ldsb]);
            gload16(Wt + woff + k0, &Bsh[ldsb]);
            __syncthreads();
            short8 af[2], bfr[2];
#pragma unroll
            for (int i = 0; i < 2; ++i) af[i] = *(const short8*)&Ash[(wm + i * 16 + fr) * 32 + fko];
#pragma unroll
            for (int j = 0; j < 2; ++j) bfr[j] = *(const short8*)&Bsh[(wn + j * 16 + fr) * 32 + fko];
#pragma unroll
            for (int i = 0; i < 2; ++i)
#pragma unroll
                for (int j = 0; j < 2; ++j)
                    acc[i][j] = __builtin_amdgcn_mfma_f32_16x16x32_bf16(af[i], bfr[j], acc[i][j], 0, 0, 0);
            __syncthreads();
        }
        const int r0 = m0 + wm + (lane >> 4) * 4;
#pragma unroll
        for (int i = 0; i < 2; ++i)
#pragma unroll
            for (int j = 0; j < 2; ++j) {
                int n = n0 + wn + j * 16 + fr;
                float bv = tb[n];
#pragma unroll
                for (int r = 0; r < 4; ++r) {
                    int m = r0 + i * 16 + r;
                    Cqkv[(size_t)m * 1536 + n] = f2bf(acc[i][j][r] + bv);
                }
            }
    }
}

// ---------------- mega2: r-qkv (bx<24) + up (bx>=24), both mfma3, shared A = fa hi/lo ----
__global__ __launch_bounds__(256) void mega2_kernel(
    const unsigned short* __restrict__ Fh, const unsigned short* __restrict__ Fl,
    const unsigned short* __restrict__ WrH, const unsigned short* __restrict__ WrL,
    const float* __restrict__ rb, float* __restrict__ Cr,
    const unsigned short* __restrict__ WcH, const unsigned short* __restrict__ WcL,
    const float* __restrict__ bcv, float* __restrict__ Cup)
{
    __shared__ unsigned short Ash[64 * 32];
    __shared__ unsigned short Asl[64 * 32];
    __shared__ unsigned short Bsh[64 * 32];
    __shared__ unsigned short Bsl[64 * 32];
    const int tid = threadIdx.x, wave = tid >> 6, lane = tid & 63;
    const int bx = blockIdx.x, m0 = blockIdx.y * 64;
    const bool rq = bx < 24;
    const int n0 = rq ? bx * 64 : (bx - 24) * 64;
    const unsigned short* Wh = rq ? WrH : WcH;
    const unsigned short* Wl = rq ? WrL : WcL;
    const float* bias = rq ? rb : bcv;
    const int sr = lane >> 2, sc = (lane & 3) * 8;
    const size_t aoff = (size_t)(m0 + wave * 16 + sr) * 512 + sc;
    const size_t woff = (size_t)(n0 + wave * 16 + sr) * 512 + sc;
    const int wm = (wave >> 1) * 32, wn = (wave & 1) * 32;
    const int fr = lane & 15, fko = (lane >> 4) * 8;
    const int ldsb = (wave * 16) * 32;

    floatx4 acc[2][2];
#pragma unroll
    for (int i = 0; i < 2; ++i)
#pragma unroll
        for (int j = 0; j < 2; ++j) acc[i][j] = (floatx4){0.f, 0.f, 0.f, 0.f};

    for (int k0 = 0; k0 < 512; k0 += 32) {
        gload16(Fh + aoff + k0, &Ash[ldsb]);
        gload16(Fl + aoff + k0, &Asl[ldsb]);
        gload16(Wh + woff + k0, &Bsh[ldsb]);
        gload16(Wl + woff + k0, &Bsl[ldsb]);
        __syncthreads();
        short8 ah[2], al[2], bh[2], bl[2];
#pragma unroll
        for (int i = 0; i < 2; ++i) {
            ah[i] = *(const short8*)&Ash[(wm + i * 16 + fr) * 32 + fko];
            al[i] = *(const short8*)&Asl[(wm + i * 16 + fr) * 32 + fko];
        }
#pragma unroll
        for (int j = 0; j < 2; ++j) {
            bh[j] = *(const short8*)&Bsh[(wn + j * 16 + fr) * 32 + fko];
            bl[j] = *(const short8*)&Bsl[(wn + j * 16 + fr) * 32 + fko];
        }
#pragma unroll
        for (int i = 0; i < 2; ++i)
#pragma unroll
            for (int j = 0; j < 2; ++j) {
                acc[i][j] = __builtin_amdgcn_mfma_f32_16x16x32_bf16(al[i], bh[j], acc[i][j], 0, 0, 0);
                acc[i][j] = __builtin_amdgcn_mfma_f32_16x16x32_bf16(ah[i], bl[j], acc[i][j], 0, 0, 0);
                acc[i][j] = __builtin_amdgcn_mfma_f32_16x16x32_bf16(ah[i], bh[j], acc[i][j], 0, 0, 0);
            }
        __syncthreads();
    }
    const int r0 = m0 + wm + (lane >> 4) * 4;
#pragma unroll
    for (int i = 0; i < 2; ++i)
#pragma unroll
        for (int j = 0; j < 2; ++j) {
            int n = n0 + wn + j * 16 + fr;
            float bv = bias[n];
#pragma unroll
            for (int r = 0; r < 4; ++r) {
                int m = r0 + i * 16 + r;
                float v = acc[i][j][r] + bv;
                if (rq) Cr[(size_t)m * 1536 + n] = v;
                else    Cup[(size_t)m * 512 + n] = v;
            }
        }
}

// ---------------- TEL attention: one block per (batch, head); bf16 out ----------------
template <typename T>
__global__ __launch_bounds__(256) void attn_kernel(const T* __restrict__ qkv, unsigned short* __restrict__ outb)
{
    const int b = blockIdx.x >> 3;
    const int h = blockIdx.x & 7;
    __shared__ float qs[32][65], ks[32][65], vs[32][65];
    __shared__ float ps[32][33];
    const int tid = threadIdx.x;
    for (int i = tid; i < 2048; i += 256) {
        int s = i >> 6, d = i & 63;
        size_t base = ((size_t)(b * 32 + s)) * 1536 + h * 64 + d;
        qs[s][d] = ldv(qkv, base);
        ks[s][d] = ldv(qkv, base + 512);
        vs[s][d] = ldv(qkv, base + 1024);
    }
    __syncthreads();
    for (int i = tid; i < 1024; i += 256) {
        int si = i >> 5, sj = i & 31;
        float acc = 0.f;
#pragma unroll 8
        for (int d = 0; d < 64; ++d) acc += qs[si][d] * ks[sj][d];
        ps[si][sj] = acc * 0.125f;
    }
    __syncthreads();
    if (tid < 32) {
        float mx = -1e30f;
        for (int j = 0; j < 32; ++j) mx = fmaxf(mx, ps[tid][j]);
        float sum = 0.f;
        for (int j = 0; j < 32; ++j) { float e = __expf(ps[tid][j] - mx); ps[tid][j] = e; sum += e; }
        float inv = 1.f / sum;
        for (int j = 0; j < 32; ++j) ps[tid][j] *= inv;
    }
    __syncthreads();
    for (int i = tid; i < 2048; i += 256) {
        int s = i >> 6, d = i & 63;
        float acc = 0.f;
#pragma unroll 8
        for (int k = 0; k < 32; ++k) acc += ps[s][k] * vs[k][d];
        outb[((size_t)(b * 32 + s)) * 512 + h * 64 + d] = f2bf(acc);
    }
}

// ---------------- complex self-attention: LDS-resident, grid (128 batch, 2 half) ----------
__global__ __launch_bounds__(256) void cattn2_kernel(const float* __restrict__ LL,
                                                     unsigned short* __restrict__ outHi,
                                                     unsigned short* __restrict__ outLo)
{
    extern __shared__ float Xs[];
    __shared__ float Pr[16][33], Pi[16][33];
    const int b = blockIdx.x, half = blockIdx.y;
    const int tid = threadIdx.x;
    const float* base = LL + (size_t)b * 16384;
    for (int i = tid; i < 16384; i += 256) {
        int c = i >> 9, e = i & 511;
        Xs[e * 32 + ((c ^ e) & 31)] = base[i];
    }
    __syncthreads();
    {
        const int li0 = tid >> 5, li1 = li0 + 8;
        const int ci0 = half * 16 + li0, ci1 = half * 16 + li1;
        const int ck = tid & 31;
        float ar0 = 0.f, ai0 = 0.f, ar1 = 0.f, ai1 = 0.f;
        for (int er = 0; er < 256; ++er) {
            const int sw = er & 31;
            float yr = Xs[er * 32 + ((ck ^ sw) & 31)];
            float yi = Xs[(er + 256) * 32 + ((ck ^ sw) & 31)];
            float xr0 = Xs[er * 32 + ((ci0 ^ sw) & 31)];
            float xi0 = Xs[(er + 256) * 32 + ((ci0 ^ sw) & 31)];
            float xr1 = Xs[er * 32 + ((ci1 ^ sw) & 31)];
            float xi1 = Xs[(er + 256) * 32 + ((ci1 ^ sw) & 31)];
            ar0 += xr0 * yr - xi0 * yi;  ai0 += xr0 * yi + xi0 * yr;
            ar1 += xr1 * yr - xi1 * yi;  ai1 += xr1 * yi + xi1 * yr;
        }
        Pr[li0][ck] = ar0 * 0.0625f;  Pi[li0][ck] = ai0 * 0.0625f;
        Pr[li1][ck] = ar1 * 0.0625f;  Pi[li1][ck] = ai1 * 0.0625f;
    }
    __syncthreads();
    if (tid < 32) {
        int r = tid & 15;
        float (*P)[33] = (tid < 16) ? Pr : Pi;
        float mx = -1e30f;
        for (int j = 0; j < 32; ++j) mx = fmaxf(mx, P[r][j]);
        float s = 0.f;
        for (int j = 0; j < 32; ++j) { float e = __expf(P[r][j] - mx); P[r][j] = e; s += e; }
        float inv = 1.f / s;
        for (int j = 0; j < 32; ++j) P[r][j] *= inv;
    }
    __syncthreads();
    const int er = tid;
    const int sw = er & 31;
    float accr[16], acci[16];
#pragma unroll
    for (int t = 0; t < 16; ++t) { accr[t] = 0.f; acci[t] = 0.f; }
    for (int k = 0; k < 32; ++k) {
        float yr = Xs[er * 32 + ((k ^ sw) & 31)];
        float yi = Xs[(er + 256) * 32 + ((k ^ sw) & 31)];
#pragma unroll
        for (int t = 0; t < 16; ++t) {
            float pr = Pr[t][k], pi = Pi[t][k];
            accr[t] += pr * yr - pi * yi;
            acci[t] += pr * yi + pi * yr;
        }
    }
#pragma unroll
    for (int t = 0; t < 16; ++t) {
        int c = half * 16 + t;
        float vr = Xs[er * 32 + ((c ^ sw) & 31)] + accr[t];
        float vi = Xs[(er + 256) * 32 + ((c ^ sw) & 31)] + acci[t];
        size_t ir = (size_t)b * 16384 + (size_t)c * 512 + er;
        unsigned short hr = f2bf(vr), hi2 = f2bf(vi);
        outHi[ir] = hr;        outLo[ir] = f2bf(vr - bf2f(hr));
        outHi[ir + 256] = hi2; outLo[ir + 256] = f2bf(vi - bf2f(hi2));
    }
}

// ---------------- residual add + LayerNorm (512), optional 2nd summand + bf16 copy ------
template <int WBF, int Y2>
__global__ __launch_bounds__(256) void add_ln_kernel(const float* __restrict__ resid, const float* __restrict__ y,
                                                     const float* __restrict__ y2,
                                                     const float* __restrict__ w, const float* __restrict__ b,
                                                     float* __restrict__ outf, unsigned short* __restrict__ outb)
{
    const int row = blockIdx.x;
    const int tid = threadIdx.x;
    const size_t base = (size_t)row * 512;
    float v0 = resid[base + tid] + y[base + tid];
    float v1 = resid[base + 256 + tid] + y[base + 256 + tid];
    if (Y2) { v0 += y2[base + tid]; v1 += y2[base + 256 + tid]; }
    float s = v0 + v1, q = v0 * v0 + v1 * v1;
    for (int off = 32; off; off >>= 1) { s += __shfl_down(s, off); q += __shfl_down(q, off); }
    __shared__ float sw[4], qw[4], ms, is;
    int wid = tid >> 6, lane = tid & 63;
    if (lane == 0) { sw[wid] = s; qw[wid] = q; }
    __syncthreads();
    if (tid == 0) {
        float S = sw[0] + sw[1] + sw[2] + sw[3];
        float Q = qw[0] + qw[1] + qw[2] + qw[3];
        float m = S * (1.f / 512.f);
        ms = m;
        is = rsqrtf(Q * (1.f / 512.f) - m * m + 1e-5f);
    }
    __syncthreads();
    float m = ms, inv = is;
    float o0 = (v0 - m) * inv * w[tid] + b[tid];
    float o1 = (v1 - m) * inv * w[256 + tid] + b[256 + tid];
    outf[base + tid] = o0;
    outf[base + 256 + tid] = o1;
    if (WBF) { outb[base + tid] = f2bf(o0); outb[base + 256 + tid] = f2bf(o1); }
}

// ---------------- relu + LayerNorm over (C,S)=16384 per batch, optional final add -------
template <int ADDF>
__global__ __launch_bounds__(256) void relu_bln_kernel(const float* __restrict__ xin,
                                                       const float* __restrict__ w, const float* __restrict__ b,
                                                       const float* __restrict__ addsrc,
                                                       float* __restrict__ out)
{
    const int bb = blockIdx.x;
    const int tid = threadIdx.x;
    const float* xp = xin + (size_t)bb * 16384;
    float s = 0.f, q = 0.f;
    for (int i = tid; i < 16384; i += 256) { float v = fmaxf(xp[i], 0.f); s += v; q += v * v; }
    for (int off = 32; off; off >>= 1) { s += __shfl_down(s, off); q += __shfl_down(q, off); }
    __shared__ float sw[4], qw[4], ms, is;
    int wid = tid >> 6, lane = tid & 63;
    if (lane == 0) { sw[wid] = s; qw[wid] = q; }
    __syncthreads();
    if (tid == 0) {
        float S = sw[0] + sw[1] + sw[2] + sw[3];
        float Q = qw[0] + qw[1] + qw[2] + qw[3];
        float m = S * (1.f / 16384.f);
        ms = m;
        is = rsqrtf(Q * (1.f / 16384.f) - m * m + 1e-5f);
    }
    __syncthreads();
    float m = ms, inv = is;
    const float* ap = ADDF ? (addsrc + (size_t)bb * 16384) : nullptr;
    float* op = out + (size_t)bb * 16384;
    for (int i = tid; i < 16384; i += 256) {
        float v = fmaxf(xp[i], 0.f);
        float o = (v - m) * inv * w[i] + b[i];
        if (ADDF) o += ap[i];
        op[i] = o;
    }
}

extern "C" void kernel_launch(void* const* d_in, const int* in_sizes, int n_in,
                              void* d_out, int out_size, void* d_ws, size_t ws_size,
                              hipStream_t stream)
{
    (void)in_sizes; (void)n_in; (void)out_size; (void)ws_size;
    const float* x        = (const float*)d_in[0];
    const float* t_in_w   = (const float*)d_in[1];
    const float* t_in_b   = (const float*)d_in[2];
    const float* t_out_w  = (const float*)d_in[3];
    const float* t_out_b  = (const float*)d_in[4];
    const float* t_ln1_w  = (const float*)d_in[5];
    const float* t_ln1_b  = (const float*)d_in[6];
    const float* t_lin1_w = (const float*)d_in[7];
    const float* t_lin1_b = (const float*)d_in[8];
    const float* t_lin2_w = (const float*)d_in[9];
    const float* t_lin2_b = (const float*)d_in[10];
    const float* t_ln2_w  = (const float*)d_in[11];
    const float* t_ln2_b  = (const float*)d_in[12];
    const float* r_in_w   = (const float*)d_in[13];
    const float* r_in_b   = (const float*)d_in[14];
    const float* r_out_w  = (const float*)d_in[15];
    const float* r_out_b  = (const float*)d_in[16];
    const float* r_ln1_w  = (const float*)d_in[17];
    const float* r_ln1_b  = (const float*)d_in[18];
    const float* r_lin1_w = (const float*)d_in[19];
    const float* r_lin1_b = (const float*)d_in[20];
    const float* r_lin2_w = (const float*)d_in[21];
    const float* r_lin2_b = (const float*)d_in[22];
    const float* r_ln2_w  = (const float*)d_in[23];
    const float* r_ln2_b  = (const float*)d_in[24];
    const float* lc_w     = (const float*)d_in[25];
    const float* lc_b     = (const float*)d_in[26];
    const float* up1_w    = (const float*)d_in[27];
    const float* up1_b    = (const float*)d_in[28];
    const float* up2_w    = (const float*)d_in[29];
    const float* up2_b    = (const float*)d_in[30];
    const float* n1_w     = (const float*)d_in[31];
    const float* n1_b     = (const float*)d_in[32];
    const float* n2_w     = (const float*)d_in[33];
    const float* n2_b     = (const float*)d_in[34];
    const float* l1_re    = (const float*)d_in[35];
    const float* l1_im    = (const float*)d_in[36];
    const float* lb1_re   = (const float*)d_in[39];
    const float* lb1_im   = (const float*)d_in[40];

    float* outp = (float*)d_out;

    // ---- workspace (float offsets; total 21,774,336 f = 87.1 MB, validated size) ----
    float* WS   = (float*)d_ws;
    float* WaF  = WS + 0;          // 262144 Wa f32 -> rinLo ushort [0:393216 f)
    float* WmF  = WS + 262144;     // 262144 Wm f32 (tail covered by rinLo span)
    float* LB   = WS + 524288;     // 16384: [0:512) lb, [512:1024) zeros, [1024:1536) bc
    float* BIGf = WS + 540672;     // 6291456: prep transients | r-qkv f32 | BIGu bf16 | BbF
    float* Cc   = WS + 6832128;    // 2097152: fa_hi/lo -> AabU -> x1r -> AabU -> x1
    float* Ee   = WS + 8929280;    // 2097152: tab -> WmH/L [0:262144) + WcH/L [262144:524288) -> t partials/x2
    float* LLp  = WS + 11026432;   // 2097152: low f32 -> r partials -> x2r -> rf
    float* FAp  = WS + 13123584;   // 2097152: WaH/L [0:262144) -> fa f32
    float* U1f  = WS + 15220736;   // 1048576 (2M u): x_hi -> x1b
    float* U2f  = WS + 16269312;   // 1048576: x_lo -> LL_hi -> x1rb
    float* U3f  = WS + 17317888;   // 1048576: LL_lo -> t-attn out
    float* WBf  = WS + 18366464;   // 3407872: ushort weights (6815744)

    float* BbF  = BIGf + 4194304;
    float* tabC = Ee;
    float* tabS = Ee + 131072;
    unsigned short* BIGu    = (unsigned short*)BIGf;
    unsigned short* AabU    = (unsigned short*)Cc;
    unsigned short* FaHiU   = (unsigned short*)Cc;
    unsigned short* FaLoU   = (unsigned short*)(Cc + 1048576);
    unsigned short* rinLoU  = (unsigned short*)WaF;            // 786432 u after cvt2
    unsigned short* WaHu    = (unsigned short*)FAp;
    unsigned short* WaLu    = (unsigned short*)(FAp + 131072);
    unsigned short* WmHu    = (unsigned short*)Ee;
    unsigned short* WmLu    = (unsigned short*)(Ee + 131072);
    unsigned short* WcHu    = (unsigned short*)(Ee + 262144);
    unsigned short* WcLu    = (unsigned short*)(Ee + 393216);
    unsigned short* up2loU  = (unsigned short*)BIGf;           // prep transient [0:131072 f)
    unsigned short* up1THu  = (unsigned short*)(BIGf + 131072);
    unsigned short* up1TLu  = (unsigned short*)(BIGf + 262144);
    float*          scrapF  = BIGf + 524288;                   // Wc f32 scrap (262144)
    unsigned short* U1u     = (unsigned short*)U1f;
    unsigned short* U2u     = (unsigned short*)U2f;
    unsigned short* U3u     = (unsigned short*)U3f;
    unsigned short* WB      = (unsigned short*)WBf;
    float* bc = LB + 1024;
    float* ZB = LB + 512;

    unsigned short* w_tin  = WB + 0;        // 1536x512
    unsigned short* w_tout = WB + 786432;   // 512x512
    unsigned short* w_tl1  = WB + 1048576;  // 2048x512
    unsigned short* w_tl2  = WB + 2097152;  // 512x2048
    unsigned short* w_rin  = WB + 3145728;  // 1536x512
    unsigned short* w_rout = WB + 3932160;  // 512x512
    unsigned short* w_rl1  = WB + 4194304;  // 2048x512
    unsigned short* w_rl2  = WB + 5242880;  // 512x2048
    unsigned short* w_up2  = WB + 6553600;  // 512x512 (A-hi for Wc prep GEMM)

    dim3 blk(256);

    // ---- prep ----
    tab_kernel<<<dim3(512), blk, 0, stream>>>(tabC, tabS);
    wa_kernel<<<dim3(512, 2), blk, 0, stream>>>(l1_re, l1_im, tabC, tabS, WaF);
    wm_kernel<<<dim3(512, 2), blk, 0, stream>>>(lc_w, tabC, tabS, WmF);
    cvt2_kernel<<<dim3(2048), blk, 0, stream>>>(WS, WaHu, WaLu, WmHu, WmLu);
    wcvt_kernel<<<dim3(30724), blk, 0, stream>>>(t_in_w, t_out_w, t_lin1_w, t_lin2_w,
                                                 r_in_w, r_out_w, r_lin1_w, r_lin2_w,
                                                 up1_w, up2_w, WB,
                                                 lb1_re, lb1_im, LB,
                                                 up2_w, up2loU, r_in_w, rinLoU);
    up1t_kernel<<<dim3(1024), blk, 0, stream>>>(up1_w, up1THu, up1TLu);
    bc_kernel<<<dim3(2), blk, 0, stream>>>(up1_b, up2_w, up2_b, bc);
    gemm_mfma3<64,64,0,0,1><<<dim3(8, 8), blk, 0, stream>>>(w_up2, up2loU, up1THu, up1TLu, ZB,
                                                            scrapF, nullptr, WcHu, WcLu, 512, 512);
    xsplit_kernel<<<dim3(2048), blk, 0, stream>>>(x, U1u, U2u, outp + NOUT, NOUT);  // + down_x

    // ---- main ----
    mega1_kernel<<<dim3(32, 64), blk, 0, stream>>>(U1u, U2u, WaHu, WaLu, LB, LLp,
                                                   w_tin, t_in_b, BIGu);                          // low + t-qkv
    cattn2_kernel<<<dim3(128, 2), blk, 65536, stream>>>(LLp, U2u, U3u);                           // LL hi/lo
    gemm_mfma3<64,64,0,1,1><<<dim3(8, 64), blk, 0, stream>>>(U2u, U3u, WmHu, WmLu, lc_b,
                                                             FAp, outp + 2 * NOUT, FaHiU, FaLoU, 512, 512); // fa
    attn_kernel<unsigned short><<<dim3(1024), blk, 0, stream>>>(BIGu, U3u);                       // t-attn (early)
    mega2_kernel<<<dim3(32, 64), blk, 0, stream>>>(FaHiU, FaLoU, w_rin, rinLoU, r_in_b, BIGf,
                                                   WcHu, WcLu, bc, outp + 3 * NOUT);              // r-qkv + up

    attn_kernel<float><<<dim3(1024), blk, 0, stream>>>(BIGf, AabU);                               // r-attn
    gemm_mfma<64,64,0,1,0,1><<<dim3(8, 64, 2), blk, 0, stream>>>(AabU, w_rout, r_out_b, BbF, LLp, nullptr, 512, 512);
    add_ln_kernel<1,1><<<dim3(4096), blk, 0, stream>>>(FAp, BbF, LLp, r_ln1_w, r_ln1_b, Cc, U2u); // x1r
    gemm_mfma<64,128,1,0,1,0><<<dim3(16, 64), blk, 0, stream>>>(U2u, w_rl1, r_lin1_b, nullptr, nullptr, BIGu, 2048, 512);
    gemm_mfma<64,64,0,1,0,1><<<dim3(8, 64, 2), blk, 0, stream>>>(BIGu, w_rl2, r_lin2_b, BbF, LLp, nullptr, 512, 2048);
    add_ln_kernel<0,1><<<dim3(4096), blk, 0, stream>>>(Cc, BbF, LLp, r_ln2_w, r_ln2_b, LLp, nullptr); // x2r
    relu_bln_kernel<0><<<dim3(128), blk, 0, stream>>>(LLp, n2_w, n2_b, nullptr, LLp);                 // rf

    gemm_mfma<64,64,0,1,0,1><<<dim3(8, 64, 2), blk, 0, stream>>>(U3u, w_tout, t_out_b, BbF, Ee, nullptr, 512, 512);
    add_ln_kernel<1,1><<<dim3(4096), blk, 0, stream>>>(x, BbF, Ee, t_ln1_w, t_ln1_b, Cc, U1u);        // x1
    gemm_mfma<64,128,1,0,1,0><<<dim3(16, 64), blk, 0, stream>>>(U1u, w_tl1, t_lin1_b, nullptr, nullptr, BIGu, 2048, 512);
    gemm_mfma<64,64,0,1,0,1><<<dim3(8, 64, 2), blk, 0, stream>>>(BIGu, w_tl2, t_lin2_b, BbF, Ee, nullptr, 512, 2048);
    add_ln_kernel<0,1><<<dim3(4096), blk, 0, stream>>>(Cc, BbF, Ee, t_ln2_w, t_ln2_b, Ee, nullptr);   // x2
    relu_bln_kernel<1><<<dim3(128), blk, 0, stream>>>(Ee, n1_w, n1_b, LLp, outp);                     // res = df + rf
}